// Round 4
// baseline (4835.802 us; speedup 1.0000x reference)
//
#include <hip/hip_runtime.h>
#include <hip/hip_bf16.h>

#define DEV __device__ __forceinline__

// tree-reduce float2 over T threads (T need not be pow2); all threads get result
DEV float2 blk_reduce2(float2* red, float2 v, int t, int T) {
  red[t] = v;
  __syncthreads();
  int s = 1; while (s < T) s <<= 1; s >>= 1;
  for (; s > 0; s >>= 1) {
    if (t < s && t + s < T) { red[t].x += red[t + s].x; red[t].y += red[t + s].y; }
    __syncthreads();
  }
  return red[0];
}

// ---------------- rope tables: ct/st [784][16] ----------------
__global__ void k_rope(float* ct, float* st) {
  int idx = blockIdx.x * 256 + threadIdx.x;
  if (idx >= 784 * 16) return;
  int n = idx >> 4, j = idx & 15;
  float inv = powf(10000.f, -(float)(2 * j) / 32.f);
  float ang = (float)n * inv;
  ct[idx] = cosf(ang);
  st[idx] = sinf(ang);
}

// ---------------- conv 3x3 s2 p1 + LN -> x_out ----------------
// grid 8*784 blocks, 192 threads (one per out channel)
__global__ __launch_bounds__(192) void k_conv_ln(const float* __restrict__ x,
    const float* __restrict__ w, const float* __restrict__ g, const float* __restrict__ bb,
    float* __restrict__ xout) {
  int blk = blockIdx.x, b = blk / 784, m = blk % 784;
  int ho = m / 28, wo = m % 28;
  __shared__ float patch[864];
  __shared__ float2 red[192];
  int t = threadIdx.x;
  for (int idx = t; idx < 864; idx += 192) {
    int k9 = idx / 96, ci = idx % 96;
    int kr = k9 / 3, kc = k9 % 3;
    int hi = 2 * ho - 1 + kr, wi = 2 * wo - 1 + kc;
    float v = 0.f;
    if (hi >= 0 && hi < 56 && wi >= 0 && wi < 56)
      v = x[((size_t)b * 3136 + hi * 56 + wi) * 96 + ci];
    patch[idx] = v;
  }
  __syncthreads();
  const float* wr = w + (size_t)t * 864;  // [co][ci][3][3], co = t
  float acc = 0.f;
  for (int ci = 0; ci < 96; ++ci) {
#pragma unroll
    for (int k9 = 0; k9 < 9; ++k9)
      acc += patch[k9 * 96 + ci] * wr[ci * 9 + k9];
  }
  float2 s = blk_reduce2(red, make_float2(acc, acc * acc), t, 192);
  float mean = s.x / 192.f, var = s.y / 192.f - mean * mean;
  float rstd = rsqrtf(var + 1e-5f);
  xout[(size_t)blk * 192 + t] = (acc - mean) * rstd * g[t] + bb[t];
}

// ---------------- xn = LN(x); k = xn@kw.T ; v = xn@vw.T ----------------
// grid 8*3136 blocks, 192 threads
__global__ __launch_bounds__(192) void k_kv(const float* __restrict__ x,
    const float* __restrict__ gin, const float* __restrict__ bin,
    const float* __restrict__ kw, const float* __restrict__ vw,
    float* __restrict__ kk, float* __restrict__ vv) {
  int blk = blockIdx.x;
  __shared__ float xn[96];
  __shared__ float2 red[192];
  int t = threadIdx.x;
  float val = (t < 96) ? x[(size_t)blk * 96 + t] : 0.f;
  float2 s = blk_reduce2(red, make_float2(val, val * val), t, 192);
  float mean = s.x / 96.f, var = s.y / 96.f - mean * mean;
  float rstd = rsqrtf(var + 1e-5f);
  if (t < 96) xn[t] = (val - mean) * rstd * gin[t] + bin[t];
  __syncthreads();
  if (t < 96) {
    const float* r = kw + (size_t)t * 96;
    float a = 0.f;
    for (int i = 0; i < 96; ++i) a += xn[i] * r[i];
    kk[(size_t)blk * 96 + t] = a;
  }
  {
    const float* r = vw + (size_t)t * 96;
    float a = 0.f;
    for (int i = 0; i < 96; ++i) a += xn[i] * r[i];
    vv[(size_t)blk * 192 + t] = a;
  }
}

// ---------------- q = LN(x_out; ln_out) @ qw.T ----------------
// grid 8*784, 192 threads
__global__ __launch_bounds__(192) void k_qproj(const float* __restrict__ xout,
    const float* __restrict__ g, const float* __restrict__ bb,
    const float* __restrict__ qw, float* __restrict__ q) {
  int blk = blockIdx.x, t = threadIdx.x;
  __shared__ float xn[192];
  __shared__ float2 red[192];
  float val = xout[(size_t)blk * 192 + t];
  float2 s = blk_reduce2(red, make_float2(val, val * val), t, 192);
  float mean = s.x / 192.f, var = s.y / 192.f - mean * mean;
  float rstd = rsqrtf(var + 1e-5f);
  xn[t] = (val - mean) * rstd * g[t] + bb[t];
  __syncthreads();
  if (t < 96) {
    const float* r = qw + (size_t)t * 192;
    float a = 0.f;
    for (int i = 0; i < 192; ++i) a += xn[i] * r[i];
    q[(size_t)blk * 96 + t] = a;
  }
}

// ---------------- pass1: per-input softmax stats over deduped <=9 neighbors ----------------
// grid 98 x 256 (one thread per (b,n))
__global__ void k_pass1(const float* __restrict__ kk, const float* __restrict__ q,
    const float* __restrict__ rpb, const float* __restrict__ tau,
    float* __restrict__ M, float* __restrict__ Z) {
  int id = blockIdx.x * 256 + threadIdx.x;
  if (id >= 8 * 3136) return;
  int b = id / 3136, n = id % 3136;
  int r = n / 56, c = n % 56, r0 = r >> 1, c0 = c >> 1;
  int oi[9];
#pragma unroll
  for (int kki = 0; kki < 9; ++kki) {
    int dr = kki / 3 - 1, dc = kki % 3 - 1;
    int rr = min(max(r0 + dr, 0), 27), cc = min(max(c0 + dc, 0), 27);
    oi[kki] = rr * 28 + cc;
  }
  float scale = expf(tau[0]);
  const float* kr = kk + (size_t)id * 96;
  float lg[9]; bool keep[9];
  float mx = -1e30f;
#pragma unroll
  for (int kki = 0; kki < 9; ++kki) {
    bool kp = true;
#pragma unroll
    for (int k2 = kki + 1; k2 < 9; ++k2) if (oi[k2] == oi[kki]) kp = false;
    keep[kki] = kp;
    if (kp) {
      const float* qr = q + ((size_t)b * 784 + oi[kki]) * 96;
      float d = 0.f;
      for (int i = 0; i < 96; ++i) d += kr[i] * qr[i];
      lg[kki] = d * scale + rpb[kki];
      mx = fmaxf(mx, lg[kki]);
    } else lg[kki] = -1e30f;
  }
  float z = 0.f;
#pragma unroll
  for (int kki = 0; kki < 9; ++kki) if (keep[kki]) z += expf(lg[kki] - mx);
  M[id] = mx; Z[id] = z;
}

// ---------------- pass2: gather contributors, upd, /denom, LN, residual ----------------
// grid 8*784, 192 threads
__global__ __launch_bounds__(192) void k_pass2(const float* __restrict__ kk,
    const float* __restrict__ q, const float* __restrict__ vv,
    const float* __restrict__ M, const float* __restrict__ Z,
    const float* __restrict__ rpb, const float* __restrict__ tau,
    const float* __restrict__ g, const float* __restrict__ bb, float* __restrict__ xout) {
  int blk = blockIdx.x, b = blk / 784, m = blk % 784;
  int r2 = m / 28, c2 = m % 28;
  int r0lo = (r2 == 0) ? 0 : r2 - 1, r0hi = (r2 == 27) ? 27 : r2 + 1;
  int c0lo = (c2 == 0) ? 0 : c2 - 1, c0hi = (c2 == 27) ? 27 : c2 + 1;
  int nrow = 2 * (r0hi - r0lo + 1), ncol = 2 * (c0hi - c0lo + 1);
  int cnt = nrow * ncol;  // <= 36
  __shared__ float qm[96], p[36];
  __shared__ int nlist[36];
  __shared__ float2 red[192];
  int t = threadIdx.x;
  if (t < 96) qm[t] = q[(size_t)blk * 96 + t];
  __syncthreads();
  if (t < cnt) {
    int rr = 2 * r0lo + t / ncol, cc = 2 * c0lo + t % ncol;
    int n = rr * 56 + cc, rr0 = rr >> 1, cc0 = cc >> 1;
    int kkf = 0;
#pragma unroll
    for (int kki = 0; kki < 9; ++kki) {
      int dr = kki / 3 - 1, dc = kki % 3 - 1;
      int ra = min(max(rr0 + dr, 0), 27), ca = min(max(cc0 + dc, 0), 27);
      if (ra == r2 && ca == c2) kkf = kki;  // last-kk-wins (matches numpy overwrite)
    }
    const float* krow = kk + ((size_t)b * 3136 + n) * 96;
    float d = 0.f;
    for (int i = 0; i < 96; ++i) d += krow[i] * qm[i];
    float scale = expf(tau[0]);
    float lg = d * scale + rpb[kkf];
    size_t idn = (size_t)b * 3136 + n;
    p[t] = expf(lg - M[idn]) / Z[idn];
    nlist[t] = n;
  }
  __syncthreads();
  float denom = 0.f;
  for (int jn = 0; jn < cnt; ++jn) denom += p[jn];
  float acc = 0.f;
  for (int jn = 0; jn < cnt; ++jn)
    acc += p[jn] * vv[((size_t)b * 3136 + nlist[jn]) * 192 + t];
  float upd = acc / (denom + 1e-8f);
  float2 s = blk_reduce2(red, make_float2(upd, upd * upd), t, 192);
  float mean = s.x / 192.f, var = s.y / 192.f - mean * mean;
  float rstd = rsqrtf(var + 1e-5f);
  xout[(size_t)blk * 192 + t] += (upd - mean) * rstd * g[t] + bb[t];
}

// ---------------- lin1: h1 = gelu( (optional LN(x)) @ w1.T + b1 ) ----------------
// grid 8*784, blockDim = hid (384 or 576)
__global__ void k_lin1(const float* __restrict__ xout,
    const float* __restrict__ lg, const float* __restrict__ lb, int hasln,
    const float* __restrict__ w1, const float* __restrict__ b1, float* __restrict__ h1) {
  int blk = blockIdx.x, t = threadIdx.x, hid = blockDim.x;
  __shared__ float xin[192];
  __shared__ float2 red[576];
  if (t < 192) xin[t] = xout[(size_t)blk * 192 + t];
  if (hasln) {
    float v = (t < 192) ? xin[t] : 0.f;
    float2 s = blk_reduce2(red, make_float2(v, v * v), t, hid);
    float mean = s.x / 192.f, var = s.y / 192.f - mean * mean;
    float rstd = rsqrtf(var + 1e-5f);
    if (t < 192) xin[t] = (xin[t] - mean) * rstd * lg[t] + lb[t];
  }
  __syncthreads();
  const float* r = w1 + (size_t)t * 192;
  float a = b1[t];
  for (int i = 0; i < 192; ++i) a += xin[i] * r[i];
  float ge = 0.5f * a * (1.f + erff(a * 0.70710678118654752f));
  h1[(size_t)blk * hid + t] = ge;
}

// ---------------- lin2: t = h @ w2.T + b2 ; optional postLN ; x_out += ----------------
// grid 8*784, 192 threads
__global__ __launch_bounds__(192) void k_lin2(const float* __restrict__ hin,
    const float* __restrict__ w2, const float* __restrict__ b2v, int hid,
    const float* __restrict__ pg, const float* __restrict__ pb, int postln,
    float* __restrict__ xout) {
  int blk = blockIdx.x, t = threadIdx.x;
  __shared__ float h[576];
  __shared__ float2 red[192];
  for (int i = t; i < hid; i += 192) h[i] = hin[(size_t)blk * hid + i];
  __syncthreads();
  const float* r = w2 + (size_t)t * hid;
  float a = b2v[t];
  for (int i = 0; i < hid; ++i) a += h[i] * r[i];
  if (postln) {
    float2 s = blk_reduce2(red, make_float2(a, a * a), t, 192);
    float mean = s.x / 192.f, var = s.y / 192.f - mean * mean;
    float rstd = rsqrtf(var + 1e-5f);
    a = (a - mean) * rstd * pg[t] + pb[t];
  }
  xout[(size_t)blk * 192 + t] += a;
}

// ---------------- qkv = LN(x; ln1) @ qkvw.T, rope on q/k, scatter to q3/k3/v3 ----------------
// grid 8*784, 576 threads
__global__ __launch_bounds__(576) void k_qkv(const float* __restrict__ xout,
    const float* __restrict__ lg, const float* __restrict__ lb,
    const float* __restrict__ qkvw, const float* __restrict__ ct, const float* __restrict__ st,
    float* __restrict__ q3, float* __restrict__ k3, float* __restrict__ v3) {
  int blk = blockIdx.x, b = blk / 784, m = blk % 784, t = threadIdx.x;
  __shared__ float xin[192], raw[576];
  __shared__ float2 red[576];
  float v = (t < 192) ? xout[(size_t)blk * 192 + t] : 0.f;
  float2 s = blk_reduce2(red, make_float2(v, v * v), t, 576);
  float mean = s.x / 192.f, var = s.y / 192.f - mean * mean;
  float rstd = rsqrtf(var + 1e-5f);
  if (t < 192) xin[t] = (v - mean) * rstd * lg[t] + lb[t];
  __syncthreads();
  {
    const float* r = qkvw + (size_t)t * 192;
    float a = 0.f;
    for (int i = 0; i < 192; ++i) a += xin[i] * r[i];
    raw[t] = a;
  }
  __syncthreads();
  int sec = t / 192, d = t % 192, h = d / 32, dh = d % 32;
  float val;
  if (sec < 2) {
    int j = dh >> 1;
    float cc = ct[m * 16 + j], ss = st[m * 16 + j];
    float me = raw[t], pa = raw[t ^ 1];
    val = (dh & 1) ? (me * cc + pa * ss) : (me * cc - pa * ss);
  } else val = raw[t];
  float* dst = (sec == 0) ? q3 : ((sec == 1) ? k3 : v3);
  dst[(((size_t)b * 6 + h) * 784 + m) * 32 + dh] = val;
}

// ---------------- neighborhood attention 7x7 ----------------
// one wave per (b,h,pixel); grid 9408 x 256 (4 waves/block)
// NOTE: all __shfl calls are executed by all 64 lanes (wave-uniform).
__global__ __launch_bounds__(256) void k_attn(const float* __restrict__ q3,
    const float* __restrict__ k3, const float* __restrict__ v3, float* __restrict__ ob) {
  int unit = blockIdx.x * 4 + (threadIdx.x >> 6);
  int l = threadIdx.x & 63;
  int b = unit / (6 * 784), rem = unit % (6 * 784), h = rem / 784, m = rem % 784;
  int i = m / 28, j = m % 28;
  int ib = min(max(i, 3), 24) - 3, jb = min(max(j, 3), 24) - 3;
  const float* qrow = q3 + (((size_t)b * 6 + h) * 784 + m) * 32;
  float logit = -1e30f;
  if (l < 49) {
    int nk = (ib + l / 7) * 28 + (jb + l % 7);
    const float* krow = k3 + (((size_t)b * 6 + h) * 784 + nk) * 32;
    float a = 0.f;
#pragma unroll
    for (int d = 0; d < 32; ++d) a += qrow[d] * krow[d];
    logit = a * 0.17677669529663687f;  // 32^-0.5
  }
  float mx = logit;
  for (int off = 32; off; off >>= 1) mx = fmaxf(mx, __shfl_xor(mx, off));
  float p = (l < 49) ? expf(logit - mx) : 0.f;
  float sum = p;
  for (int off = 32; off; off >>= 1) sum += __shfl_xor(sum, off);
  // PV: ALL 64 lanes run the shuffle loop (lanes >=32 duplicate d = l&31)
  int d = l & 31;
  float acc = 0.f;
  for (int kki = 0; kki < 49; ++kki) {
    float pk = __shfl(p, kki);
    int nk = (ib + kki / 7) * 28 + (jb + kki % 7);
    acc += pk * v3[(((size_t)b * 6 + h) * 784 + nk) * 32 + d];
  }
  if (l < 32)
    ob[(((size_t)b * 784 + m) * 6 + h) * 32 + l] = acc / sum;
}

extern "C" void kernel_launch(void* const* d_in, const int* in_sizes, int n_in,
                              void* d_out, int out_size, void* d_ws, size_t ws_size,
                              hipStream_t stream) {
  (void)in_sizes; (void)n_in; (void)out_size; (void)ws_size;
  const float* x        = (const float*)d_in[0];
  const float* convw    = (const float*)d_in[1];
  const float* qw       = (const float*)d_in[2];
  const float* kw       = (const float*)d_in[3];
  const float* vw       = (const float*)d_in[4];
  const float* ln_in_g  = (const float*)d_in[5];
  const float* ln_in_b  = (const float*)d_in[6];
  const float* ln_out_g = (const float*)d_in[7];
  const float* ln_out_b = (const float*)d_in[8];
  const float* ln_at_g  = (const float*)d_in[9];
  const float* ln_at_b  = (const float*)d_in[10];
  const float* ln_ml_g  = (const float*)d_in[11];
  const float* ln_ml_b  = (const float*)d_in[12];
  const float* gw1      = (const float*)d_in[13];
  const float* gb1      = (const float*)d_in[14];
  const float* gw2      = (const float*)d_in[15];
  const float* gb2      = (const float*)d_in[16];
  const float* tau      = (const float*)d_in[17];
  const float* rpb      = (const float*)d_in[18];
  const float* bln1g    = (const float*)d_in[19];
  const float* bln1b    = (const float*)d_in[20];
  const float* bln2g    = (const float*)d_in[21];
  const float* bln2b    = (const float*)d_in[22];
  const float* bqkvw    = (const float*)d_in[23];
  const float* bprojw   = (const float*)d_in[24];
  const float* bprojb   = (const float*)d_in[25];
  const float* bmw1     = (const float*)d_in[26];
  const float* bmb1     = (const float*)d_in[27];
  const float* bmw2     = (const float*)d_in[28];
  const float* bmb2     = (const float*)d_in[29];

  // residual stream lives directly in d_out (f32, exactly 8*784*192 elements;
  // k_conv_ln fully overwrites it first -> deterministic under graph replay)
  float* XOUT = (float*)d_out;

  float* W = (float*)d_ws;
  size_t off = 0;
  float* Qb   = W + off; off += (size_t)8 * 784 * 96;    // group phase
  float* Kb   = W + off; off += (size_t)8 * 3136 * 96;   // group phase
  float* Vb   = W + off; off += (size_t)8 * 3136 * 192;  // group phase
  float* Mb   = W + off; off += (size_t)8 * 3136;
  float* Zb   = W + off; off += (size_t)8 * 3136;
  float* H1   = W + off; off += (size_t)8 * 784 * 576;   // both phases
  float* CT   = W + off; off += (size_t)784 * 16;
  float* ST   = W + off; off += (size_t)784 * 16;
  // block phase aliases (group-phase Kb/Vb are dead by then)
  float* Q3 = Kb;                       // 1,204,224 <= 2,408,448
  float* K3 = Kb + (size_t)1204224;
  float* V3 = Vb;                       // 1,204,224 <= 4,816,896
  float* OB = Vb + (size_t)1204224;

  k_rope<<<49, 256, 0, stream>>>(CT, ST);
  k_conv_ln<<<6272, 192, 0, stream>>>(x, convw, ln_out_g, ln_out_b, XOUT);
  k_kv<<<25088, 192, 0, stream>>>(x, ln_in_g, ln_in_b, kw, vw, Kb, Vb);

  for (int it = 0; it < 3; ++it) {
    k_qproj<<<6272, 192, 0, stream>>>(XOUT, ln_out_g, ln_out_b, qw, Qb);
    k_pass1<<<98, 256, 0, stream>>>(Kb, Qb, rpb, tau, Mb, Zb);
    k_pass2<<<6272, 192, 0, stream>>>(Kb, Qb, Vb, Mb, Zb, rpb, tau, ln_at_g, ln_at_b, XOUT);
    k_lin1<<<6272, 384, 0, stream>>>(XOUT, nullptr, nullptr, 0, gw1, gb1, H1);
    k_lin2<<<6272, 192, 0, stream>>>(H1, gw2, gb2, 384, ln_ml_g, ln_ml_b, 1, XOUT);
  }

  for (int i = 0; i < 2; ++i) {
    k_qkv<<<6272, 576, 0, stream>>>(XOUT, bln1g + (size_t)i * 192, bln1b + (size_t)i * 192,
        bqkvw + (size_t)i * 576 * 192, CT, ST, Q3, K3, V3);
    k_attn<<<9408, 256, 0, stream>>>(Q3, K3, V3, OB);
    k_lin2<<<6272, 192, 0, stream>>>(OB, bprojw + (size_t)i * 192 * 192,
        bprojb + (size_t)i * 192, 192, nullptr, nullptr, 0, XOUT);
    k_lin1<<<6272, 576, 0, stream>>>(XOUT, bln2g + (size_t)i * 192, bln2b + (size_t)i * 192, 1,
        bmw1 + (size_t)i * 576 * 192, bmb1 + (size_t)i * 576, H1);
    k_lin2<<<6272, 192, 0, stream>>>(H1, bmw2 + (size_t)i * 192 * 576,
        bmb2 + (size_t)i * 192, 576, nullptr, nullptr, 0, XOUT);
  }
}

// Round 5
// 1144.619 us; speedup vs baseline: 4.2248x; 4.2248x over previous
//
#include <hip/hip_runtime.h>
#include <hip/hip_bf16.h>

#define DEV __device__ __forceinline__

// ---------------- generic transpose: src[R][C] -> dst[C][R] ----------------
__global__ void k_tr(const float* __restrict__ src, float* __restrict__ dst,
                     int R, int C) {
  int idx = blockIdx.x * 256 + threadIdx.x;
  if (idx >= R * C) return;
  int r = idx / C, c = idx % C;
  dst[(size_t)c * R + r] = src[idx];
}

// ---------------- rope tables: ct/st [784][16] ----------------
__global__ void k_rope(float* ct, float* st) {
  int idx = blockIdx.x * 256 + threadIdx.x;
  if (idx >= 784 * 16) return;
  int n = idx >> 4, j = idx & 15;
  float inv = powf(10000.f, -(float)(2 * j) / 32.f);
  float ang = (float)n * inv;
  ct[idx] = cosf(ang);
  st[idx] = sinf(ang);
}

// ---------------- LN over last dim D, wave per token, 4 tokens/block ----------------
template<int D>
__global__ __launch_bounds__(256) void k_ln(const float* __restrict__ in,
    const float* __restrict__ g, const float* __restrict__ b,
    float* __restrict__ out, int M) {
  int tok = blockIdx.x * 4 + (threadIdx.x >> 6);
  int l = threadIdx.x & 63;
  if (tok >= M) return;  // wave-uniform
  const float* row = in + (size_t)tok * D;
  constexpr int E = (D + 63) / 64;
  float v[E];
  float s = 0.f, s2 = 0.f;
#pragma unroll
  for (int e = 0; e < E; ++e) {
    int i = e * 64 + l;
    float x = (i < D) ? row[i] : 0.f;
    v[e] = x; s += x; s2 += x * x;
  }
  for (int off = 32; off; off >>= 1) { s += __shfl_xor(s, off); s2 += __shfl_xor(s2, off); }
  float mean = s / D, var = s2 / D - mean * mean;
  float rstd = rsqrtf(var + 1e-5f);
  float* orow = out + (size_t)tok * D;
#pragma unroll
  for (int e = 0; e < E; ++e) {
    int i = e * 64 + l;
    if (i < D) orow[i] = (v[e] - mean) * rstd * g[i] + b[i];
  }
}

// ---------------- LN epilogue over D=192: out = (write|add) LN(raw) ----------------
template<int ADD>
__global__ __launch_bounds__(256) void k_ln_epi(const float* __restrict__ raw,
    const float* __restrict__ g, const float* __restrict__ b,
    float* __restrict__ out, int M) {
  int tok = blockIdx.x * 4 + (threadIdx.x >> 6);
  int l = threadIdx.x & 63;
  if (tok >= M) return;
  const float* row = raw + (size_t)tok * 192;
  float v[3];
  float s = 0.f, s2 = 0.f;
#pragma unroll
  for (int e = 0; e < 3; ++e) {
    float x = row[e * 64 + l];
    v[e] = x; s += x; s2 += x * x;
  }
  for (int off = 32; off; off >>= 1) { s += __shfl_xor(s, off); s2 += __shfl_xor(s2, off); }
  float mean = s / 192.f, var = s2 / 192.f - mean * mean;
  float rstd = rsqrtf(var + 1e-5f);
  float* orow = out + (size_t)tok * 192;
#pragma unroll
  for (int e = 0; e < 3; ++e) {
    int i = e * 64 + l;
    float r = (v[e] - mean) * rstd * g[i] + b[i];
    if (ADD) orow[i] += r; else orow[i] = r;
  }
}

// ---------------- tiled GEMM: C[M][N] = A[M][K] @ WT[K][N] (+bias, epi) ----------------
// tile 32(M) x 64(N), BK=32, 256 threads, per-thread 2x4 acc.
// EPI: 0 = store, 1 = gelu+store, 2 = add-into-C
// CONV: A-loader does im2col from x[b][56][56][96] (K=864 = ci*9 + kr*3 + kc)
template<int EPI, int CONV>
__global__ __launch_bounds__(256) void k_gemm(
    const float* __restrict__ A, const float* __restrict__ WT,
    const float* __restrict__ bias, float* __restrict__ C,
    int M, int N, int K) {
  __shared__ float As[32][32];   // [k][m]
  __shared__ float Bs[32][64];   // [k][n]
  int t = threadIdx.x;
  int m0 = blockIdx.x * 32, n0 = blockIdx.y * 64;
  int c16 = t & 15, r16 = t >> 4;
  int arow = t >> 3, acol = (t & 7) * 4;
  int brow = t >> 4, bcol = (t & 15) * 4;
  float acc[2][4] = {};
  for (int kt = 0; kt < K; kt += 32) {
    // A tile
    if (CONV) {
      int m = m0 + arow;
      int b = m / 784, rem2 = m % 784, ho = rem2 / 28, wo = rem2 % 28;
#pragma unroll
      for (int j = 0; j < 4; ++j) {
        int k = kt + acol + j;
        int ci = k / 9, k9 = k % 9;
        int hi = 2 * ho - 1 + k9 / 3, wi = 2 * wo - 1 + k9 % 3;
        float v = 0.f;
        if (hi >= 0 && hi < 56 && wi >= 0 && wi < 56)
          v = A[((size_t)b * 3136 + hi * 56 + wi) * 96 + ci];
        As[acol + j][arow] = v;
      }
    } else {
      const float4 av = *(const float4*)&A[(size_t)(m0 + arow) * K + kt + acol];
      As[acol + 0][arow] = av.x; As[acol + 1][arow] = av.y;
      As[acol + 2][arow] = av.z; As[acol + 3][arow] = av.w;
    }
    // B tile: 2 float4 rows per thread
#pragma unroll
    for (int h = 0; h < 2; ++h) {
      int br = brow + h * 16;
      int n = n0 + bcol;
      float4 bv = make_float4(0.f, 0.f, 0.f, 0.f);
      if (n < N) bv = *(const float4*)&WT[(size_t)(kt + br) * N + n];
      *(float4*)&Bs[br][bcol] = bv;
    }
    __syncthreads();
#pragma unroll
    for (int k = 0; k < 32; ++k) {
      float a0 = As[k][2 * r16], a1 = As[k][2 * r16 + 1];
      float4 bv = *(const float4*)&Bs[k][4 * c16];
      acc[0][0] += a0 * bv.x; acc[0][1] += a0 * bv.y;
      acc[0][2] += a0 * bv.z; acc[0][3] += a0 * bv.w;
      acc[1][0] += a1 * bv.x; acc[1][1] += a1 * bv.y;
      acc[1][2] += a1 * bv.z; acc[1][3] += a1 * bv.w;
    }
    __syncthreads();
  }
#pragma unroll
  for (int rr = 0; rr < 2; ++rr) {
    int m = m0 + 2 * r16 + rr;
#pragma unroll
    for (int j = 0; j < 4; ++j) {
      int n = n0 + 4 * c16 + j;
      if (n >= N) continue;
      float v = acc[rr][j];
      if (bias) v += bias[n];
      if (EPI == 1) v = 0.5f * v * (1.f + erff(v * 0.70710678118654752f));
      if (EPI == 2) C[(size_t)m * N + n] += v;
      else          C[(size_t)m * N + n] = v;
    }
  }
}

// ---------------- pass1: per-input softmax stats; kkT[96][25088] coalesced ----------------
__global__ void k_pass1(const float* __restrict__ kkT, const float* __restrict__ q,
    const float* __restrict__ rpb, const float* __restrict__ tau,
    float* __restrict__ M, float* __restrict__ Z) {
  int id = blockIdx.x * 256 + threadIdx.x;
  if (id >= 8 * 3136) return;
  int b = id / 3136, n = id % 3136;
  int r = n / 56, c = n % 56, r0 = r >> 1, c0 = c >> 1;
  int oi[9];
#pragma unroll
  for (int kki = 0; kki < 9; ++kki) {
    int dr = kki / 3 - 1, dc = kki % 3 - 1;
    int rr = min(max(r0 + dr, 0), 27), cc = min(max(c0 + dc, 0), 27);
    oi[kki] = rr * 28 + cc;
  }
  float scale = expf(tau[0]);
  float lg[9]; bool keep[9];
  float mx = -1e30f;
#pragma unroll
  for (int kki = 0; kki < 9; ++kki) {
    bool kp = true;
#pragma unroll
    for (int k2 = kki + 1; k2 < 9; ++k2) if (oi[k2] == oi[kki]) kp = false;
    keep[kki] = kp;
    if (kp) {
      const float* qr = q + ((size_t)b * 784 + oi[kki]) * 96;
      float d = 0.f;
      for (int i = 0; i < 96; ++i) d += kkT[(size_t)i * 25088 + id] * qr[i];
      lg[kki] = d * scale + rpb[kki];
      mx = fmaxf(mx, lg[kki]);
    } else lg[kki] = -1e30f;
  }
  float z = 0.f;
#pragma unroll
  for (int kki = 0; kki < 9; ++kki) if (keep[kki]) z += expf(lg[kki] - mx);
  M[id] = mx; Z[id] = z;
}

// ---------------- pass2: gather contributors, upd, /denom, LN, residual ----------------
__global__ __launch_bounds__(192) void k_pass2(const float* __restrict__ kk,
    const float* __restrict__ q, const float* __restrict__ vv,
    const float* __restrict__ M, const float* __restrict__ Z,
    const float* __restrict__ rpb, const float* __restrict__ tau,
    const float* __restrict__ g, const float* __restrict__ bb, float* __restrict__ xout) {
  int blk = blockIdx.x, b = blk / 784, m = blk % 784;
  int r2 = m / 28, c2 = m % 28;
  int r0lo = (r2 == 0) ? 0 : r2 - 1, r0hi = (r2 == 27) ? 27 : r2 + 1;
  int c0lo = (c2 == 0) ? 0 : c2 - 1, c0hi = (c2 == 27) ? 27 : c2 + 1;
  int nrow = 2 * (r0hi - r0lo + 1), ncol = 2 * (c0hi - c0lo + 1);
  int cnt = nrow * ncol;  // <= 36
  __shared__ float qm[96], p[36];
  __shared__ int nlist[36];
  __shared__ float2 red[192];
  int t = threadIdx.x;
  if (t < 96) qm[t] = q[(size_t)blk * 96 + t];
  __syncthreads();
  if (t < cnt) {
    int rr = 2 * r0lo + t / ncol, cc = 2 * c0lo + t % ncol;
    int n = rr * 56 + cc, rr0 = rr >> 1, cc0 = cc >> 1;
    int kkf = 0;
#pragma unroll
    for (int kki = 0; kki < 9; ++kki) {
      int dr = kki / 3 - 1, dc = kki % 3 - 1;
      int ra = min(max(rr0 + dr, 0), 27), ca = min(max(cc0 + dc, 0), 27);
      if (ra == r2 && ca == c2) kkf = kki;  // last-kk-wins (matches numpy overwrite)
    }
    const float* krow = kk + ((size_t)b * 3136 + n) * 96;
    float d = 0.f;
    for (int i = 0; i < 96; ++i) d += krow[i] * qm[i];
    float scale = expf(tau[0]);
    float lg = d * scale + rpb[kkf];
    size_t idn = (size_t)b * 3136 + n;
    p[t] = expf(lg - M[idn]) / Z[idn];
    nlist[t] = n;
  }
  __syncthreads();
  float denom = 0.f;
  for (int jn = 0; jn < cnt; ++jn) denom += p[jn];
  float acc = 0.f;
  for (int jn = 0; jn < cnt; ++jn)
    acc += p[jn] * vv[((size_t)b * 3136 + nlist[jn]) * 192 + t];
  float upd = acc / (denom + 1e-8f);
  red[t] = make_float2(upd, upd * upd);
  __syncthreads();
  for (int s = 128; s > 0; s >>= 1) {
    if (t < s && t + s < 192) { red[t].x += red[t + s].x; red[t].y += red[t + s].y; }
    __syncthreads();
  }
  float mean = red[0].x / 192.f, var = red[0].y / 192.f - mean * mean;
  float rstd = rsqrtf(var + 1e-5f);
  xout[(size_t)blk * 192 + t] += (upd - mean) * rstd * g[t] + bb[t];
}

// ---------------- rope + scatter: RAW[6272][576] -> q3/k3/v3 [b][6][784][32] ----------------
__global__ void k_rope_scatter(const float* __restrict__ raw,
    const float* __restrict__ ct, const float* __restrict__ st,
    float* __restrict__ q3, float* __restrict__ k3, float* __restrict__ v3) {
  int idx = blockIdx.x * 256 + threadIdx.x;
  if (idx >= 8 * 784 * 576) return;
  int tok = idx / 576, d5 = idx % 576;
  int b = tok / 784, m = tok % 784;
  int sec = d5 / 192, d = d5 % 192, h = d / 32, dh = d % 32;
  float me = raw[idx], val;
  if (sec < 2) {
    float pa = raw[(size_t)tok * 576 + sec * 192 + (d ^ 1)];
    int j = dh >> 1;
    float cc = ct[m * 16 + j], ss = st[m * 16 + j];
    val = (dh & 1) ? (me * cc + pa * ss) : (me * cc - pa * ss);
  } else val = me;
  float* dst = (sec == 0) ? q3 : ((sec == 1) ? k3 : v3);
  dst[(((size_t)b * 6 + h) * 784 + m) * 32 + dh] = val;
}

// ---------------- neighborhood attention 7x7 (unchanged) ----------------
__global__ __launch_bounds__(256) void k_attn(const float* __restrict__ q3,
    const float* __restrict__ k3, const float* __restrict__ v3, float* __restrict__ ob) {
  int unit = blockIdx.x * 4 + (threadIdx.x >> 6);
  int l = threadIdx.x & 63;
  int b = unit / (6 * 784), rem = unit % (6 * 784), h = rem / 784, m = rem % 784;
  int i = m / 28, j = m % 28;
  int ib = min(max(i, 3), 24) - 3, jb = min(max(j, 3), 24) - 3;
  const float* qrow = q3 + (((size_t)b * 6 + h) * 784 + m) * 32;
  float logit = -1e30f;
  if (l < 49) {
    int nk = (ib + l / 7) * 28 + (jb + l % 7);
    const float* krow = k3 + (((size_t)b * 6 + h) * 784 + nk) * 32;
    float a = 0.f;
#pragma unroll
    for (int d = 0; d < 32; ++d) a += qrow[d] * krow[d];
    logit = a * 0.17677669529663687f;  // 32^-0.5
  }
  float mx = logit;
  for (int off = 32; off; off >>= 1) mx = fmaxf(mx, __shfl_xor(mx, off));
  float p = (l < 49) ? expf(logit - mx) : 0.f;
  float sum = p;
  for (int off = 32; off; off >>= 1) sum += __shfl_xor(sum, off);
  int d = l & 31;
  float acc = 0.f;
  for (int kki = 0; kki < 49; ++kki) {
    float pk = __shfl(p, kki);
    int nk = (ib + kki / 7) * 28 + (jb + kki % 7);
    acc += pk * v3[(((size_t)b * 6 + h) * 784 + nk) * 32 + d];
  }
  if (l < 32)
    ob[(((size_t)b * 784 + m) * 6 + h) * 32 + l] = acc / sum;
}

extern "C" void kernel_launch(void* const* d_in, const int* in_sizes, int n_in,
                              void* d_out, int out_size, void* d_ws, size_t ws_size,
                              hipStream_t stream) {
  (void)in_sizes; (void)n_in; (void)out_size; (void)ws_size;
  const float* x        = (const float*)d_in[0];
  const float* convw    = (const float*)d_in[1];
  const float* qw       = (const float*)d_in[2];
  const float* kw       = (const float*)d_in[3];
  const float* vw       = (const float*)d_in[4];
  const float* ln_in_g  = (const float*)d_in[5];
  const float* ln_in_b  = (const float*)d_in[6];
  const float* ln_out_g = (const float*)d_in[7];
  const float* ln_out_b = (const float*)d_in[8];
  const float* ln_at_g  = (const float*)d_in[9];
  const float* ln_at_b  = (const float*)d_in[10];
  const float* ln_ml_g  = (const float*)d_in[11];
  const float* ln_ml_b  = (const float*)d_in[12];
  const float* gw1      = (const float*)d_in[13];
  const float* gb1      = (const float*)d_in[14];
  const float* gw2      = (const float*)d_in[15];
  const float* gb2      = (const float*)d_in[16];
  const float* tau      = (const float*)d_in[17];
  const float* rpb      = (const float*)d_in[18];
  const float* bln1g    = (const float*)d_in[19];
  const float* bln1b    = (const float*)d_in[20];
  const float* bln2g    = (const float*)d_in[21];
  const float* bln2b    = (const float*)d_in[22];
  const float* bqkvw    = (const float*)d_in[23];
  const float* bprojw   = (const float*)d_in[24];
  const float* bprojb   = (const float*)d_in[25];
  const float* bmw1     = (const float*)d_in[26];
  const float* bmb1     = (const float*)d_in[27];
  const float* bmw2     = (const float*)d_in[28];
  const float* bmb2     = (const float*)d_in[29];

  float* XOUT = (float*)d_out;  // residual stream lives in d_out (f32, 8*784*192)

  float* W = (float*)d_ws;
  size_t off = 0;
  float* XN96  = W + off; off += (size_t)25088 * 96;   // LN(x); later aliased as KbT
  float* XN192 = W + off; off += (size_t)6272 * 192;
  float* Kb    = W + off; off += (size_t)25088 * 96;
  float* Vb    = W + off; off += (size_t)25088 * 192;
  float* Qb    = W + off; off += (size_t)6272 * 96;
  float* Mb    = W + off; off += (size_t)25088;
  float* Zb    = W + off; off += (size_t)25088;
  float* H1    = W + off; off += (size_t)6272 * 576;   // also QKVRAW
  float* T2    = W + off; off += (size_t)6272 * 192;   // also CRAW
  float* CT    = W + off; off += (size_t)784 * 16;
  float* ST    = W + off; off += (size_t)784 * 16;
  // transposed weights
  float* WTc   = W + off; off += (size_t)864 * 192;
  float* WTk   = W + off; off += (size_t)96 * 96;
  float* WTv   = W + off; off += (size_t)96 * 192;
  float* WTq   = W + off; off += (size_t)192 * 96;
  float* WTg1  = W + off; off += (size_t)192 * 384;
  float* WTg2  = W + off; off += (size_t)384 * 192;
  float* WTqkv0= W + off; off += (size_t)192 * 576;
  float* WTqkv1= W + off; off += (size_t)192 * 576;
  float* WTp0  = W + off; off += (size_t)192 * 192;
  float* WTp1  = W + off; off += (size_t)192 * 192;
  float* WTm10 = W + off; off += (size_t)192 * 576;
  float* WTm11 = W + off; off += (size_t)192 * 576;
  float* WTm20 = W + off; off += (size_t)576 * 192;
  float* WTm21 = W + off; off += (size_t)576 * 192;
  // aliases
  float* CRAW = T2;
  float* QKVRAW = H1;
  float* KbT = XN96;                    // XN96 dead after kv GEMMs
  float* Q3 = Kb;                       // block phase: Kb/Vb dead
  float* K3 = Kb + (size_t)1204224;
  float* V3 = Vb;
  float* OB = Vb + (size_t)1204224;

  auto tr = [&](const float* s, float* d, int R, int C) {
    k_tr<<<(R * C + 255) / 256, 256, 0, stream>>>(s, d, R, C);
  };
  tr(convw, WTc, 192, 864);
  tr(kw, WTk, 96, 96);
  tr(vw, WTv, 192, 96);
  tr(qw, WTq, 96, 192);
  tr(gw1, WTg1, 384, 192);
  tr(gw2, WTg2, 192, 384);
  tr(bqkvw, WTqkv0, 576, 192);  tr(bqkvw + (size_t)576 * 192, WTqkv1, 576, 192);
  tr(bprojw, WTp0, 192, 192);   tr(bprojw + (size_t)192 * 192, WTp1, 192, 192);
  tr(bmw1, WTm10, 576, 192);    tr(bmw1 + (size_t)576 * 192, WTm11, 576, 192);
  tr(bmw2, WTm20, 192, 576);    tr(bmw2 + (size_t)192 * 576, WTm21, 192, 576);
  k_rope<<<49, 256, 0, stream>>>(CT, ST);

  // conv (implicit GEMM, K=864) + LN
  k_gemm<0, 1><<<dim3(196, 3), 256, 0, stream>>>(x, WTc, nullptr, CRAW, 6272, 192, 864);
  k_ln_epi<0><<<1568, 256, 0, stream>>>(CRAW, ln_out_g, ln_out_b, XOUT, 6272);

  // k,v projections
  k_ln<96><<<6272, 256, 0, stream>>>(x, ln_in_g, ln_in_b, XN96, 25088);
  k_gemm<0, 0><<<dim3(784, 2), 256, 0, stream>>>(XN96, WTk, nullptr, Kb, 25088, 96, 96);
  k_gemm<0, 0><<<dim3(784, 3), 256, 0, stream>>>(XN96, WTv, nullptr, Vb, 25088, 192, 96);
  k_tr<<<(25088 * 96 + 255) / 256, 256, 0, stream>>>(Kb, KbT, 25088, 96);

  for (int it = 0; it < 3; ++it) {
    k_ln<192><<<1568, 256, 0, stream>>>(XOUT, ln_out_g, ln_out_b, XN192, 6272);
    k_gemm<0, 0><<<dim3(196, 2), 256, 0, stream>>>(XN192, WTq, nullptr, Qb, 6272, 96, 192);
    k_pass1<<<98, 256, 0, stream>>>(KbT, Qb, rpb, tau, Mb, Zb);
    k_pass2<<<6272, 192, 0, stream>>>(Kb, Qb, Vb, Mb, Zb, rpb, tau, ln_at_g, ln_at_b, XOUT);
    k_gemm<1, 0><<<dim3(196, 6), 256, 0, stream>>>(XOUT, WTg1, gb1, H1, 6272, 384, 192);
    k_gemm<0, 0><<<dim3(196, 3), 256, 0, stream>>>(H1, WTg2, gb2, T2, 6272, 192, 384);
    k_ln_epi<1><<<1568, 256, 0, stream>>>(T2, ln_ml_g, ln_ml_b, XOUT, 6272);
  }

  for (int i = 0; i < 2; ++i) {
    const float* wqkv = i ? WTqkv1 : WTqkv0;
    const float* wp   = i ? WTp1   : WTp0;
    const float* wm1  = i ? WTm11  : WTm10;
    const float* wm2  = i ? WTm21  : WTm20;
    k_ln<192><<<1568, 256, 0, stream>>>(XOUT, bln1g + (size_t)i * 192,
                                        bln1b + (size_t)i * 192, XN192, 6272);
    k_gemm<0, 0><<<dim3(196, 9), 256, 0, stream>>>(XN192, wqkv, nullptr, QKVRAW, 6272, 576, 192);
    k_rope_scatter<<<(8 * 784 * 576 + 255) / 256, 256, 0, stream>>>(QKVRAW, CT, ST, Q3, K3, V3);
    k_attn<<<9408, 256, 0, stream>>>(Q3, K3, V3, OB);
    k_gemm<2, 0><<<dim3(196, 3), 256, 0, stream>>>(OB, wp, bprojb + (size_t)i * 192,
                                                   XOUT, 6272, 192, 192);
    k_ln<192><<<1568, 256, 0, stream>>>(XOUT, bln2g + (size_t)i * 192,
                                        bln2b + (size_t)i * 192, XN192, 6272);
    k_gemm<1, 0><<<dim3(196, 9), 256, 0, stream>>>(XN192, wm1, bmb1 + (size_t)i * 576,
                                                   H1, 6272, 576, 192);
    k_gemm<2, 0><<<dim3(196, 3), 256, 0, stream>>>(H1, wm2, bmb2 + (size_t)i * 192,
                                                   XOUT, 6272, 192, 576);
  }
}

// Round 8
// 849.478 us; speedup vs baseline: 5.6927x; 1.3474x over previous
//
#include <hip/hip_runtime.h>
#include <hip/hip_bf16.h>

#define DEV __device__ __forceinline__

typedef __attribute__((ext_vector_type(8))) short short8;
typedef __attribute__((ext_vector_type(4))) float f32x4;

DEV unsigned short f2b(float f) {
  union { float f; unsigned u; } v; v.f = f;
  unsigned r = v.u + 0x7FFFu + ((v.u >> 16) & 1u);  // RNE
  return (unsigned short)(r >> 16);
}
DEV float b2f16(unsigned short b) {
  union { unsigned u; float f; } v; v.u = ((unsigned)b) << 16;
  return v.f;
}

// ---------------- fused weight cast f32 -> bf16 hi/lo arenas ----------------
__global__ void k_castw(const float* __restrict__ s0, const float* __restrict__ s1,
    const float* __restrict__ s2, const float* __restrict__ s3,
    const float* __restrict__ s4, const float* __restrict__ s5,
    const float* __restrict__ s6, const float* __restrict__ s7,
    const float* __restrict__ s8, const float* __restrict__ s9,
    short* __restrict__ dh, short* __restrict__ dl) {
  int idx = blockIdx.x * 256 + threadIdx.x;
  if (idx >= 1096704) return;
  const float* src; int base;
  if      (idx < 165888) { src = s0; base = 0; }
  else if (idx < 175104) { src = s1; base = 165888; }
  else if (idx < 193536) { src = s2; base = 175104; }
  else if (idx < 211968) { src = s3; base = 193536; }
  else if (idx < 285696) { src = s4; base = 211968; }
  else if (idx < 359424) { src = s5; base = 285696; }
  else if (idx < 580608) { src = s6; base = 359424; }
  else if (idx < 654336) { src = s7; base = 580608; }
  else if (idx < 875520) { src = s8; base = 654336; }
  else                   { src = s9; base = 875520; }
  float v = src[idx - base];
  unsigned short h = f2b(v);
  dh[idx] = (short)h;
  dl[idx] = (short)f2b(v - b2f16(h));
}

// ---------------- generic transpose: src[R][C] -> dst[C][R] ----------------
__global__ void k_tr(const float* __restrict__ src, float* __restrict__ dst,
                     int R, int C) {
  int idx = blockIdx.x * 256 + threadIdx.x;
  if (idx >= R * C) return;
  int r = idx / C, c = idx % C;
  dst[(size_t)c * R + r] = src[idx];
}

// ---------------- rope tables: ct/st [784][16] ----------------
__global__ void k_rope(float* ct, float* st) {
  int idx = blockIdx.x * 256 + threadIdx.x;
  if (idx >= 784 * 16) return;
  int n = idx >> 4, j = idx & 15;
  float inv = powf(10000.f, -(float)(2 * j) / 32.f);
  float ang = (float)n * inv;
  ct[idx] = cosf(ang);
  st[idx] = sinf(ang);
}

// ---------------- LN over last dim D, wave per token, 4 tokens/block ----------------
template<int D>
__global__ __launch_bounds__(256) void k_ln(const float* __restrict__ in,
    const float* __restrict__ g, const float* __restrict__ b,
    float* __restrict__ out, int M) {
  int tok = blockIdx.x * 4 + (threadIdx.x >> 6);
  int l = threadIdx.x & 63;
  if (tok >= M) return;  // wave-uniform
  const float* row = in + (size_t)tok * D;
  constexpr int E = (D + 63) / 64;
  float v[E];
  float s = 0.f, s2 = 0.f;
#pragma unroll
  for (int e = 0; e < E; ++e) {
    int i = e * 64 + l;
    float x = (i < D) ? row[i] : 0.f;
    v[e] = x; s += x; s2 += x * x;
  }
  for (int off = 32; off; off >>= 1) { s += __shfl_xor(s, off); s2 += __shfl_xor(s2, off); }
  float mean = s / D, var = s2 / D - mean * mean;
  float rstd = rsqrtf(var + 1e-5f);
  float* orow = out + (size_t)tok * D;
#pragma unroll
  for (int e = 0; e < E; ++e) {
    int i = e * 64 + l;
    if (i < D) orow[i] = (v[e] - mean) * rstd * g[i] + b[i];
  }
}

// ---------------- LN epilogue over D=192: out = (write|add) LN(raw) ----------------
template<int ADD>
__global__ __launch_bounds__(256) void k_ln_epi(const float* __restrict__ raw,
    const float* __restrict__ g, const float* __restrict__ b,
    float* __restrict__ out, int M) {
  int tok = blockIdx.x * 4 + (threadIdx.x >> 6);
  int l = threadIdx.x & 63;
  if (tok >= M) return;
  const float* row = raw + (size_t)tok * 192;
  float v[3];
  float s = 0.f, s2 = 0.f;
#pragma unroll
  for (int e = 0; e < 3; ++e) {
    float x = row[e * 64 + l];
    v[e] = x; s += x; s2 += x * x;
  }
  for (int off = 32; off; off >>= 1) { s += __shfl_xor(s, off); s2 += __shfl_xor(s2, off); }
  float mean = s / 192.f, var = s2 / 192.f - mean * mean;
  float rstd = rsqrtf(var + 1e-5f);
  float* orow = out + (size_t)tok * 192;
#pragma unroll
  for (int e = 0; e < 3; ++e) {
    int i = e * 64 + l;
    float r = (v[e] - mean) * rstd * g[i] + b[i];
    if (ADD) orow[i] += r; else orow[i] = r;
  }
}

// ---------------- MFMA bf16x2 split GEMM: C = A @ W^T, f32-grade accuracy ----------------
// 64x64 tile, BK=32, 256 threads = 4 waves (2x2), per-wave 2x2 16x16 frags.
// A f32 -> (hi,lo) bf16 during staging; W pre-split hi/lo arenas.
// Per fragment pair: acc = ah*bh + ah*bl + al*bh (al*bl dropped, ~eps^2).
// EPI: 0 = store, 1 = gelu+store, 2 = add-into-C.  CONV: im2col from x[b][56][56][96].
template<int EPI, int CONV>
__global__ __launch_bounds__(256) void k_mgemm(
    const float* __restrict__ A, const short* __restrict__ WH,
    const short* __restrict__ WL, const float* __restrict__ bias,
    float* __restrict__ C, int M, int N, int K) {
  __shared__ short AsH[64][40], AsL[64][40];
  __shared__ short BsH[64][40], BsL[64][40];
  int t = threadIdx.x;
  int m0 = blockIdx.x * 64, n0 = blockIdx.y * 64;
  int sr = t >> 2, sq = (t & 3) * 8;       // stage: row, k-offset (8 elems/thread)
  int lane = t & 63, w = t >> 6, wm = w >> 1, wn = w & 1;
  int fr = lane & 15, fq = lane >> 4;      // frag row, k-block
  f32x4 acc[2][2];
#pragma unroll
  for (int i = 0; i < 2; ++i)
#pragma unroll
    for (int j = 0; j < 2; ++j) acc[i][j] = (f32x4){0.f, 0.f, 0.f, 0.f};

  for (int kt = 0; kt < K; kt += 32) {
    // A tile: 64 rows x 32 k -> hi/lo bf16
    if (CONV) {
      int m = m0 + sr;
      int b = m / 784, rm = m % 784, ho = rm / 28, wo = rm % 28;
#pragma unroll
      for (int j = 0; j < 8; ++j) {
        int k = kt + sq + j;
        int ci = k / 9, k9 = k % 9;
        int hi = 2 * ho - 1 + k9 / 3, wi = 2 * wo - 1 + k9 % 3;
        float v = 0.f;
        if (hi >= 0 && hi < 56 && wi >= 0 && wi < 56)
          v = A[((size_t)b * 3136 + hi * 56 + wi) * 96 + ci];
        unsigned short h = f2b(v);
        AsH[sr][sq + j] = (short)h;
        AsL[sr][sq + j] = (short)f2b(v - b2f16(h));
      }
    } else {
      const float4 a0 = *(const float4*)&A[(size_t)(m0 + sr) * K + kt + sq];
      const float4 a1 = *(const float4*)&A[(size_t)(m0 + sr) * K + kt + sq + 4];
      float av[8] = {a0.x, a0.y, a0.z, a0.w, a1.x, a1.y, a1.z, a1.w};
#pragma unroll
      for (int j = 0; j < 8; ++j) {
        unsigned short h = f2b(av[j]);
        AsH[sr][sq + j] = (short)h;
        AsL[sr][sq + j] = (short)f2b(av[j] - b2f16(h));
      }
    }
    // B tile: Bs[n][k] = W[n0+n][kt+k] (pre-split bf16, 16B vector copies)
    {
      int n = n0 + sr;
      if (n < N) {
        *(short8*)&BsH[sr][sq] = *(const short8*)&WH[(size_t)n * K + kt + sq];
        *(short8*)&BsL[sr][sq] = *(const short8*)&WL[(size_t)n * K + kt + sq];
      } else {
        short8 z = {0, 0, 0, 0, 0, 0, 0, 0};
        *(short8*)&BsH[sr][sq] = z;
        *(short8*)&BsL[sr][sq] = z;
      }
    }
    __syncthreads();
    short8 ah[2], al[2], bh[2], bl[2];
#pragma unroll
    for (int s = 0; s < 2; ++s) {
      ah[s] = *(const short8*)&AsH[wm * 32 + s * 16 + fr][fq * 8];
      al[s] = *(const short8*)&AsL[wm * 32 + s * 16 + fr][fq * 8];
      bh[s] = *(const short8*)&BsH[wn * 32 + s * 16 + fr][fq * 8];
      bl[s] = *(const short8*)&BsL[wn * 32 + s * 16 + fr][fq * 8];
    }
#pragma unroll
    for (int i = 0; i < 2; ++i)
#pragma unroll
      for (int j = 0; j < 2; ++j) {
        acc[i][j] = __builtin_amdgcn_mfma_f32_16x16x32_bf16(ah[i], bh[j], acc[i][j], 0, 0, 0);
        acc[i][j] = __builtin_amdgcn_mfma_f32_16x16x32_bf16(ah[i], bl[j], acc[i][j], 0, 0, 0);
        acc[i][j] = __builtin_amdgcn_mfma_f32_16x16x32_bf16(al[i], bh[j], acc[i][j], 0, 0, 0);
      }
    __syncthreads();
  }
  // epilogue: C/D layout col = lane&15, row = (lane>>4)*4 + r   [m89]
#pragma unroll
  for (int i = 0; i < 2; ++i) {
#pragma unroll
    for (int j = 0; j < 2; ++j) {
      int n = n0 + wn * 32 + j * 16 + fr;
      if (n >= N) continue;
#pragma unroll
      for (int r = 0; r < 4; ++r) {
        int m = m0 + wm * 32 + i * 16 + fq * 4 + r;
        float v = acc[i][j][r];
        if (bias) v += bias[n];
        if (EPI == 1) v = 0.5f * v * (1.f + erff(v * 0.70710678118654752f));
        if (EPI == 2) C[(size_t)m * N + n] += v;
        else          C[(size_t)m * N + n] = v;
      }
    }
  }
}

// ---------------- pass1: per-input softmax stats; kkT[96][25088] coalesced ----------------
__global__ void k_pass1(const float* __restrict__ kkT, const float* __restrict__ q,
    const float* __restrict__ rpb, const float* __restrict__ tau,
    float* __restrict__ M, float* __restrict__ Z) {
  int id = blockIdx.x * 256 + threadIdx.x;
  if (id >= 8 * 3136) return;
  int b = id / 3136, n = id % 3136;
  int r = n / 56, c = n % 56, r0 = r >> 1, c0 = c >> 1;
  int oi[9];
#pragma unroll
  for (int kki = 0; kki < 9; ++kki) {
    int dr = kki / 3 - 1, dc = kki % 3 - 1;
    int rr = min(max(r0 + dr, 0), 27), cc = min(max(c0 + dc, 0), 27);
    oi[kki] = rr * 28 + cc;
  }
  float scale = expf(tau[0]);
  float lg[9]; bool keep[9];
  float mx = -1e30f;
#pragma unroll
  for (int kki = 0; kki < 9; ++kki) {
    bool kp = true;
#pragma unroll
    for (int k2 = kki + 1; k2 < 9; ++k2) if (oi[k2] == oi[kki]) kp = false;
    keep[kki] = kp;
    if (kp) {
      const float* qr = q + ((size_t)b * 784 + oi[kki]) * 96;
      float d = 0.f;
      for (int i = 0; i < 96; ++i) d += kkT[(size_t)i * 25088 + id] * qr[i];
      lg[kki] = d * scale + rpb[kki];
      mx = fmaxf(mx, lg[kki]);
    } else lg[kki] = -1e30f;
  }
  float z = 0.f;
#pragma unroll
  for (int kki = 0; kki < 9; ++kki) if (keep[kki]) z += expf(lg[kki] - mx);
  M[id] = mx; Z[id] = z;
}

// ---------------- pass2: gather contributors, upd, /denom, LN, residual ----------------
__global__ __launch_bounds__(192) void k_pass2(const float* __restrict__ kk,
    const float* __restrict__ q, const float* __restrict__ vv,
    const float* __restrict__ M, const float* __restrict__ Z,
    const float* __restrict__ rpb, const float* __restrict__ tau,
    const float* __restrict__ g, const float* __restrict__ bb, float* __restrict__ xout) {
  int blk = blockIdx.x, b = blk / 784, m = blk % 784;
  int r2 = m / 28, c2 = m % 28;
  int r0lo = (r2 == 0) ? 0 : r2 - 1, r0hi = (r2 == 27) ? 27 : r2 + 1;
  int c0lo = (c2 == 0) ? 0 : c2 - 1, c0hi = (c2 == 27) ? 27 : c2 + 1;
  int nrow = 2 * (r0hi - r0lo + 1), ncol = 2 * (c0hi - c0lo + 1);
  int cnt = nrow * ncol;  // <= 36
  __shared__ float qm[96], p[36];
  __shared__ int nlist[36];
  __shared__ float2 red[192];
  int t = threadIdx.x;
  if (t < 96) qm[t] = q[(size_t)blk * 96 + t];
  __syncthreads();
  if (t < cnt) {
    int rr = 2 * r0lo + t / ncol, cc = 2 * c0lo + t % ncol;
    int n = rr * 56 + cc, rr0 = rr >> 1, cc0 = cc >> 1;
    int kkf = 0;
#pragma unroll
    for (int kki = 0; kki < 9; ++kki) {
      int dr = kki / 3 - 1, dc = kki % 3 - 1;
      int ra = min(max(rr0 + dr, 0), 27), ca = min(max(cc0 + dc, 0), 27);
      if (ra == r2 && ca == c2) kkf = kki;  // last-kk-wins (matches numpy overwrite)
    }
    const float* krow = kk + ((size_t)b * 3136 + n) * 96;
    float d = 0.f;
    for (int i = 0; i < 96; ++i) d += krow[i] * qm[i];
    float scale = expf(tau[0]);
    float lg = d * scale + rpb[kkf];
    size_t idn = (size_t)b * 3136 + n;
    p[t] = expf(lg - M[idn]) / Z[idn];
    nlist[t] = n;
  }
  __syncthreads();
  float denom = 0.f;
  for (int jn = 0; jn < cnt; ++jn) denom += p[jn];
  float acc = 0.f;
  for (int jn = 0; jn < cnt; ++jn)
    acc += p[jn] * vv[((size_t)b * 3136 + nlist[jn]) * 192 + t];
  float upd = acc / (denom + 1e-8f);
  red[t] = make_float2(upd, upd * upd);
  __syncthreads();
  for (int s = 128; s > 0; s >>= 1) {
    if (t < s && t + s < 192) { red[t].x += red[t + s].x; red[t].y += red[t + s].y; }
    __syncthreads();
  }
  float mean = red[0].x / 192.f, var = red[0].y / 192.f - mean * mean;
  float rstd = rsqrtf(var + 1e-5f);
  xout[(size_t)blk * 192 + t] += (upd - mean) * rstd * g[t] + bb[t];
}

// ---------------- rope + scatter: RAW[6272][576] -> q3/k3/v3 [b][6][784][32] ----------------
__global__ void k_rope_scatter(const float* __restrict__ raw,
    const float* __restrict__ ct, const float* __restrict__ st,
    float* __restrict__ q3, float* __restrict__ k3, float* __restrict__ v3) {
  int idx = blockIdx.x * 256 + threadIdx.x;
  if (idx >= 8 * 784 * 576) return;
  int tok = idx / 576, d5 = idx % 576;
  int b = tok / 784, m = tok % 784;
  int sec = d5 / 192, d = d5 % 192, h = d / 32, dh = d % 32;
  float me = raw[idx], val;
  if (sec < 2) {
    float pa = raw[(size_t)tok * 576 + sec * 192 + (d ^ 1)];
    int j = dh >> 1;
    float cc = ct[m * 16 + j], ss = st[m * 16 + j];
    val = (dh & 1) ? (me * cc + pa * ss) : (me * cc - pa * ss);
  } else val = me;
  float* dst = (sec == 0) ? q3 : ((sec == 1) ? k3 : v3);
  dst[(((size_t)b * 6 + h) * 784 + m) * 32 + dh] = val;
}

// ---------------- neighborhood attention 7x7, XCD-chunked block swizzle ----------------
// grid = 9408 blocks x 4 waves = 37632 units = 8*6*784. 9408 = 8 * 1176.
__global__ __launch_bounds__(256) void k_attn(const float* __restrict__ q3,
    const float* __restrict__ k3, const float* __restrict__ v3, float* __restrict__ ob) {
  int bid = blockIdx.x;
  int swz = (bid & 7) * 1176 + (bid >> 3);  // bijective on [0,9408)
  int unit = swz * 4 + (threadIdx.x >> 6);
  int l = threadIdx.x & 63;
  int b = unit / (6 * 784), rem = unit % (6 * 784), h = rem / 784, m = rem % 784;
  int i = m / 28, j = m % 28;
  int ib = min(max(i, 3), 24) - 3, jb = min(max(j, 3), 24) - 3;
  const float* qrow = q3 + (((size_t)b * 6 + h) * 784 + m) * 32;
  float logit = -1e30f;
  if (l < 49) {
    int nk = (ib + l / 7) * 28 + (jb + l % 7);
    const float* krow = k3 + (((size_t)b * 6 + h) * 784 + nk) * 32;
    float a = 0.f;
#pragma unroll
    for (int d = 0; d < 32; ++d) a += qrow[d] * krow[d];
    logit = a * 0.17677669529663687f;  // 32^-0.5
  }
  float mx = logit;
  for (int off = 32; off; off >>= 1) mx = fmaxf(mx, __shfl_xor(mx, off));
  float p = (l < 49) ? expf(logit - mx) : 0.f;
  float sum = p;
  for (int off = 32; off; off >>= 1) sum += __shfl_xor(sum, off);
  int d = l & 31;
  float acc = 0.f;
  for (int kki = 0; kki < 49; ++kki) {
    float pk = __shfl(p, kki);
    int nk = (ib + kki / 7) * 28 + (jb + kki % 7);
    acc += pk * v3[(((size_t)b * 6 + h) * 784 + nk) * 32 + d];
  }
  if (l < 32)
    ob[(((size_t)b * 784 + m) * 6 + h) * 32 + l] = acc / sum;
}

extern "C" void kernel_launch(void* const* d_in, const int* in_sizes, int n_in,
                              void* d_out, int out_size, void* d_ws, size_t ws_size,
                              hipStream_t stream) {
  (void)in_sizes; (void)n_in; (void)out_size; (void)ws_size;
  const float* x        = (const float*)d_in[0];
  const float* convw    = (const float*)d_in[1];
  const float* qw       = (const float*)d_in[2];
  const float* kw       = (const float*)d_in[3];
  const float* vw       = (const float*)d_in[4];
  const float* ln_in_g  = (const float*)d_in[5];
  const float* ln_in_b  = (const float*)d_in[6];
  const float* ln_out_g = (const float*)d_in[7];
  const float* ln_out_b = (const float*)d_in[8];
  const float* ln_at_g  = (const float*)d_in[9];
  const float* ln_at_b  = (const float*)d_in[10];
  const float* ln_ml_g  = (const float*)d_in[11];
  const float* ln_ml_b  = (const float*)d_in[12];
  const float* gw1      = (const float*)d_in[13];
  const float* gb1      = (const float*)d_in[14];
  const float* gw2      = (const float*)d_in[15];
  const float* gb2      = (const float*)d_in[16];
  const float* tau      = (const float*)d_in[17];
  const float* rpb      = (const float*)d_in[18];
  const float* bln1g    = (const float*)d_in[19];
  const float* bln1b    = (const float*)d_in[20];
  const float* bln2g    = (const float*)d_in[21];
  const float* bln2b    = (const float*)d_in[22];
  const float* bqkvw    = (const float*)d_in[23];
  const float* bprojw   = (const float*)d_in[24];
  const float* bprojb   = (const float*)d_in[25];
  const float* bmw1     = (const float*)d_in[26];
  const float* bmb1     = (const float*)d_in[27];
  const float* bmw2     = (const float*)d_in[28];
  const float* bmb2     = (const float*)d_in[29];

  float* XOUT = (float*)d_out;  // residual stream lives in d_out (f32, 8*784*192)

  float* W = (float*)d_ws;
  size_t off = 0;
  float* XN96  = W + off; off += (size_t)25088 * 96;   // LN(x); later aliased as KbT
  float* XN192 = W + off; off += (size_t)6272 * 192;
  float* Kb    = W + off; off += (size_t)25088 * 96;
  float* Vb    = W + off; off += (size_t)25088 * 192;
  float* Qb    = W + off; off += (size_t)6272 * 96;
  float* Mb    = W + off; off += (size_t)25088;
  float* Zb    = W + off; off += (size_t)25088;
  float* H1    = W + off; off += (size_t)6272 * 576;   // also QKVRAW
  float* T2    = W + off; off += (size_t)6272 * 192;   // also CRAW
  float* CT    = W + off; off += (size_t)784 * 16;
  float* ST    = W + off; off += (size_t)784 * 16;
  short* WBH   = (short*)(W + off); off += (size_t)548352 + 16;  // hi arena
  short* WBL   = (short*)(W + off); off += (size_t)548352 + 16;  // lo arena
  // bf16 weight arena offsets (elements)
  const size_t O_c = 0, O_k = 165888, O_v = 175104, O_q = 193536,
               O_g1 = 211968, O_g2 = 285696, O_qkv = 359424, O_p = 580608,
               O_m1 = 654336, O_m2 = 875520;
  // aliases
  float* CRAW = T2;
  float* QKVRAW = H1;
  float* KbT = XN96;                    // XN96 dead after k/v GEMMs
  float* Q3 = Kb;                       // block phase: Kb/Vb dead
  float* K3 = Kb + (size_t)1204224;
  float* V3 = Vb;
  float* OB = Vb + (size_t)1204224;

  k_castw<<<4284, 256, 0, stream>>>(convw, kw, vw, qw, gw1, gw2, bqkvw, bprojw,
                                    bmw1, bmw2, WBH, WBL);
  k_rope<<<49, 256, 0, stream>>>(CT, ST);

  // conv (implicit GEMM, K=864) + LN
  k_mgemm<0, 1><<<dim3(98, 3), 256, 0, stream>>>(x, WBH + O_c, WBL + O_c, nullptr,
                                                 CRAW, 6272, 192, 864);
  k_ln_epi<0><<<1568, 256, 0, stream>>>(CRAW, ln_out_g, ln_out_b, XOUT, 6272);

  // k,v projections
  k_ln<96><<<6272, 256, 0, stream>>>(x, ln_in_g, ln_in_b, XN96, 25088);
  k_mgemm<0, 0><<<dim3(392, 2), 256, 0, stream>>>(XN96, WBH + O_k, WBL + O_k, nullptr,
                                                  Kb, 25088, 96, 96);
  k_mgemm<0, 0><<<dim3(392, 3), 256, 0, stream>>>(XN96, WBH + O_v, WBL + O_v, nullptr,
                                                  Vb, 25088, 192, 96);
  k_tr<<<(25088 * 96 + 255) / 256, 256, 0, stream>>>(Kb, KbT, 25088, 96);

  for (int it = 0; it < 3; ++it) {
    k_ln<192><<<1568, 256, 0, stream>>>(XOUT, ln_out_g, ln_out_b, XN192, 6272);
    k_mgemm<0, 0><<<dim3(98, 2), 256, 0, stream>>>(XN192, WBH + O_q, WBL + O_q, nullptr,
                                                   Qb, 6272, 96, 192);
    k_pass1<<<98, 256, 0, stream>>>(KbT, Qb, rpb, tau, Mb, Zb);
    k_pass2<<<6272, 192, 0, stream>>>(Kb, Qb, Vb, Mb, Zb, rpb, tau, ln_at_g, ln_at_b, XOUT);
    k_mgemm<1, 0><<<dim3(98, 6), 256, 0, stream>>>(XOUT, WBH + O_g1, WBL + O_g1, gb1,
                                                   H1, 6272, 384, 192);
    k_mgemm<0, 0><<<dim3(98, 3), 256, 0, stream>>>(H1, WBH + O_g2, WBL + O_g2, gb2,
                                                   T2, 6272, 192, 384);
    k_ln_epi<1><<<1568, 256, 0, stream>>>(T2, ln_ml_g, ln_ml_b, XOUT, 6272);
  }

  for (int i = 0; i < 2; ++i) {
    k_ln<192><<<1568, 256, 0, stream>>>(XOUT, bln1g + (size_t)i * 192,
                                        bln1b + (size_t)i * 192, XN192, 6272);
    k_mgemm<0, 0><<<dim3(98, 9), 256, 0, stream>>>(XN192, WBH + O_qkv + (size_t)i * 110592,
        WBL + O_qkv + (size_t)i * 110592, nullptr, QKVRAW, 6272, 576, 192);
    k_rope_scatter<<<(8 * 784 * 576 + 255) / 256, 256, 0, stream>>>(QKVRAW, CT, ST, Q3, K3, V3);
    k_attn<<<9408, 256, 0, stream>>>(Q3, K3, V3, OB);
    k_mgemm<2, 0><<<dim3(98, 3), 256, 0, stream>>>(OB, WBH + O_p + (size_t)i * 36864,
        WBL + O_p + (size_t)i * 36864, bprojb + (size_t)i * 192, XOUT, 6272, 192, 192);
    k_ln<192><<<1568, 256, 0, stream>>>(XOUT, bln2g + (size_t)i * 192,
                                        bln2b + (size_t)i * 192, XN192, 6272);
    k_mgemm<1, 0><<<dim3(98, 9), 256, 0, stream>>>(XN192, WBH + O_m1 + (size_t)i * 110592,
        WBL + O_m1 + (size_t)i * 110592, bmb1 + (size_t)i * 576, H1, 6272, 576, 192);
    k_mgemm<2, 0><<<dim3(98, 3), 256, 0, stream>>>(H1, WBH + O_m2 + (size_t)i * 110592,
        WBL + O_m2 + (size_t)i * 110592, bmb2 + (size_t)i * 192, XOUT, 6272, 192, 576);
  }
}